// Round 9
// baseline (73.241 us; speedup 1.0000x reference)
//
#include <hip/hip_runtime.h>
#include <math.h>

// Problem constants:
//   x:  (256, 197, 384) f32   — row 0 is CLS, rows 1..196 are "nodes"
//   ea: (256, 196, 384) f32
//   out:(256, 50, 384)  f32   — [CLS, 49 selected nodes in ascending-score order]
#define NB      256
#define NNODES  196
#define NC      384
#define SEQ     197
#define START   147          // 196//4*3
#define KEEP    49
#define OUTROWS 50
#define C4      96           // NC/4 float4 columns

#define NT      960          // 15 waves/block; 2 blocks per batch
#define CH      192          // channels per half-block
#define C4H     48           // float4 columns per half row
#define RG1     20           // row-groups in phase 1 (960/48)

// ws layout: score f32[NB][NNODES] then flag int[NB]; both zeroed per call.
#define SCORE_BYTES ((size_t)NB * NNODES * sizeof(float))
#define FLAG_BYTES  ((size_t)NB * sizeof(int))

// LDS: 30720 (partial f64) + 768 (imp) + 784 (psc) + 784 (sc) + 196 (sel)
// ~= 33.3 KB -> 2 blocks/CU well under 160 KB. No launch_bounds min-wave
// arg: round 7 showed forcing it crushes VGPR (20) and spills f64 accums.
__global__ __launch_bounds__(NT)
void pool_pair(const float* __restrict__ x,
               const float* __restrict__ ea,
               float* __restrict__ out,
               float* __restrict__ score,    // [NB][NNODES], zeroed
               int*   __restrict__ flag) {   // [NB], zeroed
    __shared__ double partial[RG1][CH];      // 30.7 KB
    __shared__ float imp[CH];                // own half's importance
    __shared__ float psc[NNODES];            // own half's partial dots
    __shared__ float sc[NNODES];             // combined scores
    __shared__ int   sel[KEEP];

    const int gb   = blockIdx.x;
    const int b    = gb >> 1;
    const int h    = gb & 1;                 // channel half
    const int tid  = threadIdx.x;            // 0..959
    const int wave = tid >> 6;
    const int lane = tid & 63;

    // ---- Phase 1: column sums of ea[:, :, 192h : 192h+192] ----
    {
        const int rg = tid / C4H;            // 0..19
        const int c4 = tid % C4H;            // 0..47
        const float4* p = (const float4*)(ea + (size_t)b * NNODES * NC) + h * C4H + c4;
        double ax = 0.0, ay = 0.0, az = 0.0, aw = 0.0;
        for (int row = rg; row < NNODES; row += RG1) {
            float4 v = p[(size_t)row * C4];  // 48 contiguous float4 per rg
            ax += v.x; ay += v.y; az += v.z; aw += v.w;
        }
        partial[rg][4 * c4 + 0] = ax;
        partial[rg][4 * c4 + 1] = ay;
        partial[rg][4 * c4 + 2] = az;
        partial[rg][4 * c4 + 3] = aw;
    }
    __syncthreads();
    if (tid < CH) {                          // own-half imp (local, no comms)
        double s = 0.0;
        #pragma unroll
        for (int rg = 0; rg < RG1; ++rg) s += partial[rg][tid];
        float m = (float)(s * (1.0 / (double)NNODES));
        imp[tid] = 1.0f / (1.0f + expf(-m));
    }
    __syncthreads();

    // ---- Phase 2: partial dots over own 192 channels (wave-per-node) ----
    {
        const float w0 = imp[lane];
        const float w1 = imp[lane + 64];
        const float w2 = imp[lane + 128];
        const float* xb = x + ((size_t)b * SEQ + 1) * NC + h * CH;
        for (int n = wave; n < NNODES; n += 15) {
            const float* row = xb + (size_t)n * NC;
            double acc = (double)row[lane]       * (double)w0
                       + (double)row[lane + 64]  * (double)w1
                       + (double)row[lane + 128] * (double)w2;
            #pragma unroll
            for (int off = 32; off > 0; off >>= 1)
                acc += __shfl_xor(acc, off);
            if (lane == 0) psc[n] = (float)acc;
        }
    }
    __syncthreads();

    // ---- Publish partial dots; pairwise sync via release/acquire flag ----
    // score[b][n] = pdot0 + pdot1: exactly 2 addends, FP add is commutative
    // -> bit-deterministic regardless of arrival order.
    if (tid < NNODES) atomicAdd(&score[(size_t)b * NNODES + tid], psc[tid]);
    __syncthreads();                          // drains vmcnt: adds performed
    if (tid == 0) {
        __threadfence();                      // device-scope release
        __hip_atomic_fetch_add(&flag[b], 1, __ATOMIC_RELEASE, __HIP_MEMORY_SCOPE_AGENT);
        long spins = 0;                       // bounded spin (escape hatch)
        while (__hip_atomic_load(&flag[b], __ATOMIC_ACQUIRE, __HIP_MEMORY_SCOPE_AGENT) < 2
               && spins < (1L << 31)) ++spins;
    }
    __syncthreads();
    if (tid < NNODES)
        sc[tid] = __hip_atomic_load(&score[(size_t)b * NNODES + tid],
                                    __ATOMIC_RELAXED, __HIP_MEMORY_SCOPE_AGENT);
    __syncthreads();

    // ---- Phase 3: stable ascending rank (duplicated in both half-blocks) ----
    if (tid < NNODES) {
        const float s = sc[tid];
        int rank = 0;
        for (int m = 0; m < NNODES; ++m) {
            const float sm = sc[m];           // m uniform -> LDS broadcast
            rank += (sm < s) || (sm == s && m < tid);   // stable tie-break
        }
        if (rank >= START) sel[rank - START] = tid;
    }
    __syncthreads();

    // ---- Phase 4: block h writes out rows [25h, 25h+25) (float4) ----
    {
        const int jg = tid / C4;              // 0..9
        const int c4 = tid % C4;
        const float* nodes   = x + ((size_t)b * SEQ + 1) * NC;
        const float4* nodes4 = (const float4*)nodes;
        const float4* cls4   = (const float4*)(x + (size_t)b * SEQ * NC);
        float4* out4         = (float4*)(out + (size_t)b * OUTROWS * NC);
        #pragma unroll
        for (int it = 0; it < 3; ++it) {
            int jj = jg + 10 * it;            // 0..29
            if (jj < 25) {
                int j = h * 25 + jj;          // 0..49
                const float4* src = (j == 0) ? cls4 : (nodes4 + (size_t)sel[j - 1] * C4);
                out4[(size_t)j * C4 + c4] = src[c4];
            }
        }
    }
}

extern "C" void kernel_launch(void* const* d_in, const int* in_sizes, int n_in,
                              void* d_out, int out_size, void* d_ws, size_t ws_size,
                              hipStream_t stream) {
    const float* x  = (const float*)d_in[0];
    const float* ea = (const float*)d_in[1];
    float* out      = (float*)d_out;
    float* score    = (float*)d_ws;
    int*   flag     = (int*)((char*)d_ws + SCORE_BYTES);

    // zero score + flag every call (graph-capture-safe, deterministic)
    hipMemsetAsync(d_ws, 0, SCORE_BYTES + FLAG_BYTES, stream);

    hipLaunchKernelGGL(pool_pair, dim3(NB * 2), dim3(NT), 0, stream,
                       x, ea, out, score, flag);
}

// Round 10
// 39.911 us; speedup vs baseline: 1.8351x; 1.8351x over previous
//
#include <hip/hip_runtime.h>
#include <math.h>

// Problem constants:
//   x:  (256, 197, 384) f32   — row 0 is CLS, rows 1..196 are "nodes"
//   ea: (256, 196, 384) f32
//   out:(256, 50, 384)  f32   — [CLS, 49 selected nodes in ascending-score order]
#define NB      256
#define NNODES  196
#define NC      384
#define SEQ     197
#define START   147          // 196//4*3
#define KEEP    49
#define OUTROWS 50
#define C4      96           // NC/4 float4 columns

#define NT      960          // 15 waves, 1 block per batch (round-2 structure)
#define RG      10           // row-groups in phase 1 (round-2 form)
#define SROWS   88           // node rows staged in LDS via global_load_lds DMA
#define SF4     (SROWS * C4) // 8448 staged float4s = 8*960 + 768

// global->LDS DMA, 16B per lane, no VGPR round-trip, no compiler discretion.
// LDS dest rule: wave-uniform base + lane*16; our mapping (flat index tid+960*i)
// is exactly lane-linear, so per-thread pointers are consistent with it.
#define GLOAD_LDS(gptr, lptr)                                                  \
    __builtin_amdgcn_global_load_lds(                                          \
        (const __attribute__((address_space(1))) void*)(gptr),                 \
        (__attribute__((address_space(3))) void*)(lptr), 16, 0, 0)

// LDS: stage 135168 + partial 15360 + imp 1536 + sc 784 + sel 196 ~= 150 KB
__global__ __launch_bounds__(NT)
void pool_dma(const float* __restrict__ x,
              const float* __restrict__ ea,
              float* __restrict__ out) {
    __shared__ alignas(16) float stage[SROWS][NC];   // 132 KB x-row stage
    __shared__ float partial[RG][NC];                // f32 partials (15 KB)
    __shared__ alignas(16) float imp[NC];
    __shared__ float sc[NNODES];
    __shared__ int   sel[KEEP];

    const int b    = blockIdx.x;
    const int tid  = threadIdx.x;                    // 0..959
    const int wave = tid >> 6;
    const int lane = tid & 63;
    const float* nodes = x + ((size_t)b * SEQ + 1) * NC;   // skip CLS

    // ---- Phase 0: issue x-row staging DMA (rows 0..87 -> LDS), THEN do the
    //      ea sums. Both HBM streams are in flight concurrently; syncthreads'
    //      vmcnt(0) drain guarantees completion. ----
    {
        const float4* gsrc = (const float4*)nodes;
        float4* lbase = (float4*)&stage[0][0];
        #pragma unroll
        for (int i = 0; i < 8; ++i)
            GLOAD_LDS(gsrc + tid + 960 * i, lbase + tid + 960 * i);
        if (tid < SF4 - 7680)                        // wave-aligned (768 = 12 waves)
            GLOAD_LDS(gsrc + tid + 7680, lbase + tid + 7680);
    }

    // ---- Phase 1: per-channel ea mean (unmodified round-2 form, f32 partials) ----
    {
        const int rg = tid / C4;                     // 0..9
        const int c4 = tid % C4;
        const float4* p = (const float4*)(ea + (size_t)b * NNODES * NC);
        double ax = 0.0, ay = 0.0, az = 0.0, aw = 0.0;
        for (int row = rg; row < NNODES; row += RG) {
            float4 v = p[(size_t)row * C4 + c4];     // coalesced
            ax += v.x; ay += v.y; az += v.z; aw += v.w;
        }
        partial[rg][4 * c4 + 0] = (float)ax;
        partial[rg][4 * c4 + 1] = (float)ay;
        partial[rg][4 * c4 + 2] = (float)az;
        partial[rg][4 * c4 + 3] = (float)aw;
    }
    __syncthreads();   // drains vmcnt(0): partials AND stage DMA complete

    if (tid < NC) {
        double s = 0.0;
        #pragma unroll
        for (int rg = 0; rg < RG; ++rg) s += (double)partial[rg][tid];
        float m = (float)(s * (1.0 / (double)NNODES));
        imp[tid] = 1.0f / (1.0f + expf(-m));
    }
    __syncthreads();

    // ---- Phase 2: wave-per-node dots; rows <SROWS from LDS, rest global ----
    {
        const float2* imp2 = (const float2*)imp;
        float2 w[3];
        #pragma unroll
        for (int j = 0; j < 3; ++j) w[j] = imp2[lane + 64 * j];

        for (int n = wave; n < NNODES; n += 15) {    // n uniform per wave
            double acc = 0.0;
            if (n < SROWS) {
                const float2* row2 = (const float2*)&stage[n][0];
                #pragma unroll
                for (int j = 0; j < 3; ++j) {
                    float2 v = row2[lane + 64 * j];  // ds_read
                    acc += (double)v.x * (double)w[j].x + (double)v.y * (double)w[j].y;
                }
            } else {
                const float2* row2 = (const float2*)(nodes + (size_t)n * NC);
                #pragma unroll
                for (int j = 0; j < 3; ++j) {
                    float2 v = row2[lane + 64 * j];  // coalesced global
                    acc += (double)v.x * (double)w[j].x + (double)v.y * (double)w[j].y;
                }
            }
            #pragma unroll
            for (int off = 32; off > 0; off >>= 1)
                acc += __shfl_xor(acc, off);
            if (lane == 0) sc[n] = (float)acc;
        }
    }
    __syncthreads();

    // ---- Phase 3: stable ascending rank; keep ranks >= START ----
    if (tid < NNODES) {
        const float s = sc[tid];
        int rank = 0;
        for (int m = 0; m < NNODES; ++m) {
            const float sm = sc[m];
            rank += (sm < s) || (sm == s && m < tid);   // stable tie-break
        }
        if (rank >= START) sel[rank - START] = tid;
    }
    __syncthreads();

    // ---- Phase 4: write output rows (float4; staged rows from LDS) ----
    {
        const int jg = tid / C4;                     // 0..9
        const int c4 = tid % C4;
        const float4* nodes4 = (const float4*)nodes;
        const float4* cls4   = (const float4*)(x + (size_t)b * SEQ * NC);
        float4* out4         = (float4*)(out + (size_t)b * OUTROWS * NC);
        #pragma unroll
        for (int it = 0; it < 5; ++it) {
            int j = jg + 10 * it;                    // 0..49
            float4 v;
            if (j == 0) {
                v = cls4[c4];
            } else {
                int n = sel[j - 1];                  // uniform within iteration
                v = (n < SROWS) ? ((const float4*)&stage[n][0])[c4]
                                : nodes4[(size_t)n * C4 + c4];
            }
            out4[(size_t)j * C4 + c4] = v;
        }
    }
}

extern "C" void kernel_launch(void* const* d_in, const int* in_sizes, int n_in,
                              void* d_out, int out_size, void* d_ws, size_t ws_size,
                              hipStream_t stream) {
    const float* x  = (const float*)d_in[0];
    const float* ea = (const float*)d_in[1];
    float* out      = (float*)d_out;

    hipLaunchKernelGGL(pool_dma, dim3(NB), dim3(NT), 0, stream, x, ea, out);
}